// Round 6
// baseline (150.725 us; speedup 1.0000x reference)
//
#include <hip/hip_runtime.h>
#include <hip/hip_bf16.h>

// MPNNConv restructured:
//   s[n] = h[n] @ W1[0:128] + b1 (f32 swz), g[n] = h[n] @ W1[128:256] (bf16 swz, L2-resident)
//   Hsum[n] = sum_{e: rows[e]=n} relu(s[n] + g[cols[e]] + ef[e] @ W1e)   (K=32 MFMA)
//   out[n]  = Hsum[n] @ W2 + deg[n]*b2
// CSR on-device. layer1 is CHUNK-BALANCED: one 2-wave block per 64 CSR
// positions; block owns all nodes STARTING in its chunk (node-aligned, no
// atomics); waves split output cols (64 each, disjoint stores, no LDS).
// All 4 tiles' ec/ef gathers issued in one batch to expose MLP.

typedef __attribute__((ext_vector_type(8))) short bf16x8;
typedef __attribute__((ext_vector_type(4))) float f32x4;

#define ND 128
#define ED 32
#define CH 64   // CSR positions per chunk

__device__ __forceinline__ short f2bf(float x) {
  unsigned int u = __float_as_uint(x);
  unsigned int r = (u + 0x7FFFu + ((u >> 16) & 1u)) >> 16;
  return (short)r;
}

__device__ __forceinline__ float bf2f(short s) {
  return __uint_as_float(((unsigned int)(unsigned short)s) << 16);
}

__device__ __forceinline__ f32x4 bf8lo(bf16x8 v) {
  f32x4 r;
  #pragma unroll
  for (int j = 0; j < 4; ++j) r[j] = bf2f(v[j]);
  return r;
}
__device__ __forceinline__ f32x4 bf8hi(bf16x8 v) {
  f32x4 r;
  #pragma unroll
  for (int j = 0; j < 4; ++j) r[j] = bf2f(v[4 + j]);
  return r;
}

__device__ __forceinline__ int load_idx(const void* ei, long long i, int is64) {
  return is64 ? (int)((const long long*)ei)[i] : ((const int*)ei)[i];
}

// swizzled offset within a 128-wide row for col c (c = ct*16 + cc):
// o = (ct>>2)*64 + (cc>>2)*16 + (ct&3)*4 + (cc&3)
__device__ __forceinline__ int swz(int c) {
  int ct = c >> 4, cc = c & 15;
  return (ct >> 2) * 64 + (cc >> 2) * 16 + (ct & 3) * 4 + (cc & 3);
}

// --- weight pre-layouts + one-time int64/int32 detect ---
__global__ __launch_bounds__(256) void prep_kernel(
    const float* __restrict__ W1, const float* __restrict__ W2,
    const unsigned int* __restrict__ ei, short* __restrict__ w12t,
    short* __restrict__ w1eA, short* __restrict__ w2t, int* __restrict__ flag) {
  if (blockIdx.x == 0 && threadIdx.x == 0) {
    int is64 = 1;
    for (int i = 0; i < 16; ++i)
      if (ei[2 * i + 1] != 0u) is64 = 0;
    flag[0] = is64;
  }
  int t = blockIdx.x * blockDim.x + threadIdx.x;
  if (t < 256 * 128) {
    int np = t >> 7, k = t & 127;
    float v = (np < 128) ? W1[k * 128 + np] : W1[(128 + k) * 128 + (np - 128)];
    w12t[t] = f2bf(v);
  }
  if (t < 128 * 128) {
    int n = t >> 7, k = t & 127;
    w2t[t] = f2bf(W2[k * 128 + n]);
  }
  if (t < 8 * 64 * 8) {  // w1eA[ct][lane][j] = W1[256+lg*8+j][ct*16+li]
    int ct = t >> 9, lane = (t >> 3) & 63, j = t & 7;
    int li = lane & 15, lg = lane >> 4;
    w1eA[t] = f2bf(W1[(256 + lg * 8 + j) * 128 + ct * 16 + li]);
  }
}

// --- histogram + per-edge rank ---
__global__ void hist_kernel(const void* __restrict__ ei, const int* __restrict__ flag,
                            int* __restrict__ counts, int* __restrict__ rank, int E) {
  int e = blockIdx.x * blockDim.x + threadIdx.x;
  if (e >= E) return;
  int r = load_idx(ei, e, flag[0]);
  rank[e] = atomicAdd(&counts[r], 1);
}

// --- single-block scan: 1024 threads x 16 elems ---
__global__ __launch_bounds__(1024) void scan_kernel(const int* __restrict__ counts,
                                                    int* __restrict__ row_ptr, int n) {
  __shared__ int wtot[16];
  int tid = threadIdx.x;
  int lane = tid & 63, w = tid >> 6;
  int base_i = tid * 16;
  int c[16];
  int tot = 0;
  #pragma unroll
  for (int j = 0; j < 16; ++j) {
    int i = base_i + j;
    c[j] = (i < n) ? counts[i] : 0;
    tot += c[j];
  }
  int x = tot;
  #pragma unroll
  for (int d = 1; d < 64; d <<= 1) {
    int t = __shfl_up(x, d);
    if (lane >= d) x += t;
  }
  if (lane == 63) wtot[w] = x;
  __syncthreads();
  if (w == 0) {
    int y = (lane < 16) ? wtot[lane] : 0;
    #pragma unroll
    for (int d = 1; d < 16; d <<= 1) {
      int t = __shfl_up(y, d);
      if (lane >= d) y += t;
    }
    if (lane < 16) wtot[lane] = y;
  }
  __syncthreads();
  int waveoff = (w == 0) ? 0 : wtot[w - 1];
  int run = waveoff + x - tot;  // exclusive prefix
  if (tid == 0) row_ptr[0] = 0;
  #pragma unroll
  for (int j = 0; j < 16; ++j) {
    int i = base_i + j;
    if (i < n) {
      run += c[j];
      row_ptr[i + 1] = run;
    }
  }
}

// --- fused: sg GEMM | ec scatter | chunk-bounds binary search ---
__global__ __launch_bounds__(256, 4) void scatter_sg_kernel(
    const void* __restrict__ ei, const int* __restrict__ flag,
    const int* __restrict__ row_ptr, const int* __restrict__ rank,
    const float* __restrict__ h, const short* __restrict__ w12t,
    const float* __restrict__ b1, int2* __restrict__ ec, int2* __restrict__ cb,
    float* __restrict__ s2, short* __restrict__ g2, int N, int E, int nchunks) {
  int b = blockIdx.x;
  int SGB = (N + 63) >> 6;
  int SCB = (E + 255) >> 8;
  if (b < SGB) {
    // ---- s = h@W1top + b1 (f32 swz), g = h@W1mid (bf16 swz)
    int lane = threadIdx.x & 63, w = threadIdx.x >> 6;
    int li = lane & 15, lg = lane >> 4;
    int base = b * 64 + w * 16;
    int rowm = base + li;
    if (rowm >= N) rowm = N - 1;
    float breg[8];
    #pragma unroll
    for (int nt = 0; nt < 8; ++nt) breg[nt] = b1[nt * 16 + li];
    f32x4 acc[16];
    #pragma unroll
    for (int nt = 0; nt < 16; ++nt) acc[nt] = (f32x4){0.f, 0.f, 0.f, 0.f};
    #pragma unroll
    for (int kc = 0; kc < 4; ++kc) {
      f32x4 f0 = *(const f32x4*)(h + (size_t)rowm * ND + kc * 32 + lg * 8);
      f32x4 f1 = *(const f32x4*)(h + (size_t)rowm * ND + kc * 32 + lg * 8 + 4);
      bf16x8 a;
      #pragma unroll
      for (int j = 0; j < 4; ++j) { a[j] = f2bf(f0[j]); a[4 + j] = f2bf(f1[j]); }
      #pragma unroll
      for (int nt = 0; nt < 16; ++nt) {
        bf16x8 bb = *(const bf16x8*)(w12t + (nt * 16 + li) * 128 + kc * 32 + lg * 8);
        acc[nt] = __builtin_amdgcn_mfma_f32_16x16x32_bf16(a, bb, acc[nt], 0, 0, 0);
      }
    }
    #pragma unroll
    for (int nt = 0; nt < 16; ++nt)
      #pragma unroll
      for (int r = 0; r < 4; ++r) {
        int row = base + lg * 4 + r;
        if (row < N) {
          if (nt < 8) {
            s2[(size_t)row * 128 + swz(nt * 16 + li)] = acc[nt][r] + breg[nt];
          } else {
            g2[(size_t)row * 128 + swz((nt - 8) * 16 + li)] = f2bf(acc[nt][r]);
          }
        }
      }
  } else if (b < SGB + SCB) {
    // ---- ec scatter (atomic-free, rank precomputed)
    int e = (b - SGB) * 256 + threadIdx.x;
    if (e < E) {
      int f = flag[0];
      int r = load_idx(ei, e, f);
      int c = load_idx(ei, (long long)E + e, f);
      ec[row_ptr[r] + rank[e]] = make_int2(e, c);
    }
  } else {
    // ---- chunk bounds: cb[k] = {first node with row_ptr>=k*CH, ... >=(k+1)*CH}
    int k = (b - SGB - SCB) * 256 + threadIdx.x;
    if (k < nchunks) {
      int t0 = k * CH, t1 = t0 + CH;
      int lo = 0, hi = N;
      while (lo < hi) { int mid = (lo + hi) >> 1; if (row_ptr[mid] < t0) lo = mid + 1; else hi = mid; }
      int na = lo;
      hi = N;
      while (lo < hi) { int mid = (lo + hi) >> 1; if (row_ptr[mid] < t1) lo = mid + 1; else hi = mid; }
      cb[k] = make_int2(na, lo);
    }
  }
}

// --- layer 1 + segment reduce: chunk-balanced, 2 waves/block split by cols ---
__global__ __launch_bounds__(128) void layer1_kernel(
    const float* __restrict__ s2, const short* __restrict__ g2,
    const float* __restrict__ ef, const int2* __restrict__ ec,
    const short* __restrict__ w1eA, const int* __restrict__ row_ptr,
    const int2* __restrict__ cb, float* __restrict__ hsum) {
  int2 bounds = cb[blockIdx.x];
  int na = bounds.x, nb = bounds.y;
  if (na >= nb) return;
  int lane = threadIdx.x & 63;
  int w = threadIdx.x >> 6;  // col half 0/1
  int li = lane & 15, lg = lane >> 4;

  bf16x8 wa[4];
  #pragma unroll
  for (int nt = 0; nt < 4; ++nt)
    wa[nt] = *(const bf16x8*)(w1eA + ((w * 4 + nt) * 64 + lane) * 8);

  for (int n = na; n < nb; ++n) {
    int rp = row_ptr[n], rpe = row_ptr[n + 1];
    int deg = rpe - rp;
    f32x4 sreg[4];
    #pragma unroll
    for (int nt = 0; nt < 4; ++nt)
      sreg[nt] = *(const f32x4*)(s2 + (size_t)n * 128 + w * 64 + lg * 16 + nt * 4);
    f32x4 psum[4];
    #pragma unroll
    for (int nt = 0; nt < 4; ++nt) psum[nt] = (f32x4){0.f, 0.f, 0.f, 0.f};

    int ntiles = (deg + 15) >> 4;
    int last = rpe - 1;
    for (int tb = 0; tb < ntiles; tb += 4) {
      int nact = ntiles - tb;
      if (nact > 4) nact = 4;
      // batch: all ec loads, then all ef loads (one latency round each)
      int2 ev[4];
      #pragma unroll
      for (int m = 0; m < 4; ++m) {
        int p = rp + (tb + m) * 16 + li;
        ev[m] = ec[p > last ? last : p];
      }
      f32x4 ea[4], eb[4];
      #pragma unroll
      for (int m = 0; m < 4; ++m) {
        const float* ep = ef + (size_t)ev[m].x * ED + lg * 8;
        ea[m] = *(const f32x4*)ep;
        eb[m] = *(const f32x4*)(ep + 4);
      }
      #pragma unroll
      for (int m = 0; m < 4; ++m) {
        if (m < nact) {
          const short* gp = g2 + (size_t)ev[m].y * 128 + w * 64 + lg * 16;
          bf16x8 g0 = *(const bf16x8*)gp;
          bf16x8 g1 = *(const bf16x8*)(gp + 8);
          bf16x8 bfrag;
          #pragma unroll
          for (int j = 0; j < 4; ++j) { bfrag[j] = f2bf(ea[m][j]); bfrag[4 + j] = f2bf(eb[m][j]); }
          f32x4 a0 = __builtin_amdgcn_mfma_f32_16x16x32_bf16(wa[0], bfrag, (f32x4){0.f,0.f,0.f,0.f}, 0, 0, 0);
          f32x4 a1 = __builtin_amdgcn_mfma_f32_16x16x32_bf16(wa[1], bfrag, (f32x4){0.f,0.f,0.f,0.f}, 0, 0, 0);
          f32x4 a2 = __builtin_amdgcn_mfma_f32_16x16x32_bf16(wa[2], bfrag, (f32x4){0.f,0.f,0.f,0.f}, 0, 0, 0);
          f32x4 a3 = __builtin_amdgcn_mfma_f32_16x16x32_bf16(wa[3], bfrag, (f32x4){0.f,0.f,0.f,0.f}, 0, 0, 0);
          if ((tb + m) * 16 + li < deg) {
            f32x4 v0 = a0 + sreg[0] + bf8lo(g0);
            f32x4 v1 = a1 + sreg[1] + bf8hi(g0);
            f32x4 v2 = a2 + sreg[2] + bf8lo(g1);
            f32x4 v3 = a3 + sreg[3] + bf8hi(g1);
            #pragma unroll
            for (int r = 0; r < 4; ++r) {
              psum[0][r] += (v0[r] > 0.f ? v0[r] : 0.f);
              psum[1][r] += (v1[r] > 0.f ? v1[r] : 0.f);
              psum[2][r] += (v2[r] > 0.f ? v2[r] : 0.f);
              psum[3][r] += (v3[r] > 0.f ? v3[r] : 0.f);
            }
          }
        }
      }
    }

    // reduce over the 16 li-lanes (edges), store this wave's col-half
    #pragma unroll
    for (int nt = 0; nt < 4; ++nt)
      #pragma unroll
      for (int r = 0; r < 4; ++r) {
        float v = psum[nt][r];
        v += __shfl_xor(v, 1);
        v += __shfl_xor(v, 2);
        v += __shfl_xor(v, 4);
        v += __shfl_xor(v, 8);
        psum[nt][r] = v;
      }
    if (li == 0) {
      #pragma unroll
      for (int nt = 0; nt < 4; ++nt)
        *(f32x4*)(hsum + (size_t)n * 128 + w * 64 + nt * 16 + lg * 4) = psum[nt];
    }
  }
}

// --- out = Hsum @ W2 + deg*b2 ; 4 waves x 16 rows per block ---
__global__ __launch_bounds__(256) void out_kernel(const float* __restrict__ hsum,
                                                  const short* __restrict__ w2t,
                                                  const float* __restrict__ b2,
                                                  const int* __restrict__ row_ptr,
                                                  float* __restrict__ out, int N) {
  int lane = threadIdx.x & 63, w = threadIdx.x >> 6;
  int li = lane & 15, lg = lane >> 4;
  int base = blockIdx.x * 64 + w * 16;
  int rowm = base + li;
  if (rowm >= N) rowm = N - 1;
  float breg[8];
  #pragma unroll
  for (int nt = 0; nt < 8; ++nt) breg[nt] = b2[nt * 16 + li];
  f32x4 acc[8];
  #pragma unroll
  for (int nt = 0; nt < 8; ++nt) acc[nt] = (f32x4){0.f, 0.f, 0.f, 0.f};
  #pragma unroll
  for (int kc = 0; kc < 4; ++kc) {
    f32x4 f0 = *(const f32x4*)(hsum + (size_t)rowm * 128 + kc * 32 + lg * 8);
    f32x4 f1 = *(const f32x4*)(hsum + (size_t)rowm * 128 + kc * 32 + lg * 8 + 4);
    bf16x8 a;
    #pragma unroll
    for (int j = 0; j < 4; ++j) { a[j] = f2bf(f0[j]); a[4 + j] = f2bf(f1[j]); }
    #pragma unroll
    for (int nt = 0; nt < 8; ++nt) {
      bf16x8 bb = *(const bf16x8*)(w2t + (nt * 16 + li) * 128 + kc * 32 + lg * 8);
      acc[nt] = __builtin_amdgcn_mfma_f32_16x16x32_bf16(a, bb, acc[nt], 0, 0, 0);
    }
  }
  #pragma unroll
  for (int r = 0; r < 4; ++r) {
    int row = base + lg * 4 + r;
    if (row < N) {
      float dg = (float)(row_ptr[row + 1] - row_ptr[row]);
      #pragma unroll
      for (int nt = 0; nt < 8; ++nt)
        out[(size_t)row * 128 + nt * 16 + li] = acc[nt][r] + dg * breg[nt];
    }
  }
}

extern "C" void kernel_launch(void* const* d_in, const int* in_sizes, int n_in,
                              void* d_out, int out_size, void* d_ws, size_t ws_size,
                              hipStream_t stream) {
  const float* h  = (const float*)d_in[0];
  const void*  ei = d_in[1];
  const float* ef = (const float*)d_in[2];
  const float* W1 = (const float*)d_in[4];
  const float* b1 = (const float*)d_in[5];
  const float* W2 = (const float*)d_in[6];
  const float* b2 = (const float*)d_in[7];
  float* out = (float*)d_out;
  int N = in_sizes[0] / ND;
  int E = in_sizes[2] / ED;
  int nchunks = (E + CH - 1) / CH;

  char* ws = (char*)d_ws;
  size_t off = 0;
  auto alloc = [&](size_t bytes) {
    size_t o = off;
    off = (off + bytes + 255) & ~(size_t)255;
    return o;
  };
  int*   flag    = (int*)(ws + alloc(4));
  int*   counts  = (int*)(ws + alloc((size_t)N * 4));
  int*   row_ptr = (int*)(ws + alloc((size_t)(N + 1) * 4));
  int*   rank    = (int*)(ws + alloc((size_t)E * 4));
  short* w12t    = (short*)(ws + alloc(256 * 128 * 2));
  short* w1eA    = (short*)(ws + alloc(8 * 64 * 8 * 2));
  short* w2t     = (short*)(ws + alloc(128 * 128 * 2));
  float* s2      = (float*)(ws + alloc((size_t)N * 128 * 4));
  short* g2      = (short*)(ws + alloc((size_t)N * 128 * 2));
  float* hsumb   = (float*)(ws + alloc((size_t)N * 128 * 4));
  int2*  ec      = (int2*)(ws + alloc((size_t)E * 8));
  int2*  cbb     = (int2*)(ws + alloc((size_t)nchunks * 8));

  int SGB = (N + 63) >> 6;
  int SCB = (E + 255) >> 8;
  int CBB = (nchunks + 255) >> 8;

  hipMemsetAsync(counts, 0, (size_t)N * 4, stream);
  prep_kernel<<<128, 256, 0, stream>>>(W1, W2, (const unsigned int*)ei, w12t, w1eA, w2t, flag);
  hist_kernel<<<(E + 255) / 256, 256, 0, stream>>>(ei, flag, counts, rank, E);
  scan_kernel<<<1, 1024, 0, stream>>>(counts, row_ptr, N);
  scatter_sg_kernel<<<SGB + SCB + CBB, 256, 0, stream>>>(
      ei, flag, row_ptr, rank, h, w12t, b1, ec, cbb, s2, g2, N, E, nchunks);
  layer1_kernel<<<nchunks, 128, 0, stream>>>(s2, g2, ef, ec, w1eA, row_ptr, cbb, hsumb);
  out_kernel<<<(N + 63) / 64, 256, 0, stream>>>(hsumb, w2t, b2, row_ptr, out, N);
}

// Round 7
// 139.107 us; speedup vs baseline: 1.0835x; 1.0835x over previous
//
#include <hip/hip_runtime.h>
#include <hip/hip_bf16.h>

// MPNNConv restructured:
//   s[n] = h[n] @ W1[0:128] + b1 (f32 swz), g[n] = h[n] @ W1[128:256] (bf16 swz, L2-resident)
//   Hsum[n] = sum_{e: rows[e]=n} relu(s[n] + g[cols[e]] + ef[e] @ W1e)   (K=32 MFMA)
//   out[n]  = Hsum[n] @ W2 + deg[n]*b2
// CSR on-device. ef is permuted into CSR order as bf16 (efb) SCATTER-side
// (scattered writes are fire-and-forget: measured 2.3 TB/s vs ~1 TB/s for
// dependent gather reads). layer1 streams efb/ccol coalesced, chunk-balanced
// (2-wave block per 64 CSR positions, col-split), gathers only L2-resident g.

typedef __attribute__((ext_vector_type(8))) short bf16x8;
typedef __attribute__((ext_vector_type(4))) float f32x4;

#define ND 128
#define ED 32
#define CH 64   // CSR positions per layer1 chunk

__device__ __forceinline__ short f2bf(float x) {
  unsigned int u = __float_as_uint(x);
  unsigned int r = (u + 0x7FFFu + ((u >> 16) & 1u)) >> 16;
  return (short)r;
}

__device__ __forceinline__ float bf2f(short s) {
  return __uint_as_float(((unsigned int)(unsigned short)s) << 16);
}

__device__ __forceinline__ f32x4 bf8lo(bf16x8 v) {
  f32x4 r;
  #pragma unroll
  for (int j = 0; j < 4; ++j) r[j] = bf2f(v[j]);
  return r;
}
__device__ __forceinline__ f32x4 bf8hi(bf16x8 v) {
  f32x4 r;
  #pragma unroll
  for (int j = 0; j < 4; ++j) r[j] = bf2f(v[4 + j]);
  return r;
}

__device__ __forceinline__ int load_idx(const void* ei, long long i, int is64) {
  return is64 ? (int)((const long long*)ei)[i] : ((const int*)ei)[i];
}

// swizzled offset within a 128-wide row for col c (c = ct*16 + cc):
// o = (ct>>2)*64 + (cc>>2)*16 + (ct&3)*4 + (cc&3)
__device__ __forceinline__ int swz(int c) {
  int ct = c >> 4, cc = c & 15;
  return (ct >> 2) * 64 + (cc >> 2) * 16 + (ct & 3) * 4 + (cc & 3);
}

// --- weight pre-layouts + int64/int32 detect + zero counts ---
__global__ __launch_bounds__(256) void prep_kernel(
    const float* __restrict__ W1, const float* __restrict__ W2,
    const unsigned int* __restrict__ ei, short* __restrict__ w12t,
    short* __restrict__ w1eA, short* __restrict__ w2t, int* __restrict__ flag,
    int* __restrict__ counts, int N) {
  if (blockIdx.x == 0 && threadIdx.x == 0) {
    int is64 = 1;
    for (int i = 0; i < 16; ++i)
      if (ei[2 * i + 1] != 0u) is64 = 0;
    flag[0] = is64;
  }
  int t = blockIdx.x * blockDim.x + threadIdx.x;
  for (int i = t; i < N; i += 32768) counts[i] = 0;
  if (t < 256 * 128) {
    int np = t >> 7, k = t & 127;
    float v = (np < 128) ? W1[k * 128 + np] : W1[(128 + k) * 128 + (np - 128)];
    w12t[t] = f2bf(v);
  }
  if (t < 128 * 128) {
    int n = t >> 7, k = t & 127;
    w2t[t] = f2bf(W2[k * 128 + n]);
  }
  if (t < 8 * 64 * 8) {  // w1eA[ct][lane][j] = W1[256+lg*8+j][ct*16+li]
    int ct = t >> 9, lane = (t >> 3) & 63, j = t & 7;
    int li = lane & 15, lg = lane >> 4;
    w1eA[t] = f2bf(W1[(256 + lg * 8 + j) * 128 + ct * 16 + li]);
  }
}

// --- histogram + rank + packed (row,col) so ei is never read again ---
__global__ void hist_kernel(const void* __restrict__ ei, const int* __restrict__ flag,
                            int* __restrict__ counts, int* __restrict__ rank,
                            unsigned int* __restrict__ rc, int E) {
  int e = blockIdx.x * blockDim.x + threadIdx.x;
  if (e >= E) return;
  int f = flag[0];
  int r = load_idx(ei, e, f);
  int c = load_idx(ei, (long long)E + e, f);
  rank[e] = atomicAdd(&counts[r], 1);
  rc[e] = ((unsigned int)r << 16) | (unsigned int)c;   // N < 65536
}

// --- single-block scan: 1024 threads x 16 elems ---
__global__ __launch_bounds__(1024) void scan_kernel(const int* __restrict__ counts,
                                                    int* __restrict__ row_ptr, int n) {
  __shared__ int wtot[16];
  int tid = threadIdx.x;
  int lane = tid & 63, w = tid >> 6;
  int base_i = tid * 16;
  int c[16];
  int tot = 0;
  #pragma unroll
  for (int j = 0; j < 16; ++j) {
    int i = base_i + j;
    c[j] = (i < n) ? counts[i] : 0;
    tot += c[j];
  }
  int x = tot;
  #pragma unroll
  for (int d = 1; d < 64; d <<= 1) {
    int t = __shfl_up(x, d);
    if (lane >= d) x += t;
  }
  if (lane == 63) wtot[w] = x;
  __syncthreads();
  if (w == 0) {
    int y = (lane < 16) ? wtot[lane] : 0;
    #pragma unroll
    for (int d = 1; d < 16; d <<= 1) {
      int t = __shfl_up(y, d);
      if (lane >= d) y += t;
    }
    if (lane < 16) wtot[lane] = y;
  }
  __syncthreads();
  int waveoff = (w == 0) ? 0 : wtot[w - 1];
  int run = waveoff + x - tot;  // exclusive prefix
  if (tid == 0) row_ptr[0] = 0;
  #pragma unroll
  for (int j = 0; j < 16; ++j) {
    int i = base_i + j;
    if (i < n) {
      run += c[j];
      row_ptr[i + 1] = run;
    }
  }
}

// --- fused: sg GEMM | ef->efb permute (scatter-side) | chunk bounds ---
__global__ __launch_bounds__(256, 4) void scatter_sg_kernel(
    const float* __restrict__ ef, const int* __restrict__ row_ptr,
    const int* __restrict__ rank, const unsigned int* __restrict__ rc,
    const float* __restrict__ h, const short* __restrict__ w12t,
    const float* __restrict__ b1, short* __restrict__ efb,
    unsigned short* __restrict__ ccol, int2* __restrict__ cb,
    float* __restrict__ s2, short* __restrict__ g2, int N, int E, int nchunks) {
  int b = blockIdx.x;
  int SGB = (N + 63) >> 6;
  int SCB = (4 * E + 255) >> 8;
  if (b < SGB) {
    // ---- s = h@W1top + b1 (f32 swz), g = h@W1mid (bf16 swz)
    int lane = threadIdx.x & 63, w = threadIdx.x >> 6;
    int li = lane & 15, lg = lane >> 4;
    int base = b * 64 + w * 16;
    int rowm = base + li;
    if (rowm >= N) rowm = N - 1;
    float breg[8];
    #pragma unroll
    for (int nt = 0; nt < 8; ++nt) breg[nt] = b1[nt * 16 + li];
    f32x4 acc[16];
    #pragma unroll
    for (int nt = 0; nt < 16; ++nt) acc[nt] = (f32x4){0.f, 0.f, 0.f, 0.f};
    #pragma unroll
    for (int kc = 0; kc < 4; ++kc) {
      f32x4 f0 = *(const f32x4*)(h + (size_t)rowm * ND + kc * 32 + lg * 8);
      f32x4 f1 = *(const f32x4*)(h + (size_t)rowm * ND + kc * 32 + lg * 8 + 4);
      bf16x8 a;
      #pragma unroll
      for (int j = 0; j < 4; ++j) { a[j] = f2bf(f0[j]); a[4 + j] = f2bf(f1[j]); }
      #pragma unroll
      for (int nt = 0; nt < 16; ++nt) {
        bf16x8 bb = *(const bf16x8*)(w12t + (nt * 16 + li) * 128 + kc * 32 + lg * 8);
        acc[nt] = __builtin_amdgcn_mfma_f32_16x16x32_bf16(a, bb, acc[nt], 0, 0, 0);
      }
    }
    #pragma unroll
    for (int nt = 0; nt < 16; ++nt)
      #pragma unroll
      for (int r = 0; r < 4; ++r) {
        int row = base + lg * 4 + r;
        if (row < N) {
          if (nt < 8) {
            s2[(size_t)row * 128 + swz(nt * 16 + li)] = acc[nt][r] + breg[nt];
          } else {
            g2[(size_t)row * 128 + swz((nt - 8) * 16 + li)] = f2bf(acc[nt][r]);
          }
        }
      }
  } else if (b < SGB + SCB) {
    // ---- permute: 4 threads/edge; coalesced ef read, 64B-merged scattered write
    int gt = (b - SGB) * 256 + threadIdx.x;
    int e = gt >> 2, part = gt & 3;
    if (e < E) {
      unsigned int p = rc[e];
      int r = (int)(p >> 16), c = (int)(p & 0xffffu);
      int pos = row_ptr[r] + rank[e];
      f32x4 a0 = *(const f32x4*)(ef + (size_t)e * ED + part * 8);
      f32x4 a1 = *(const f32x4*)(ef + (size_t)e * ED + part * 8 + 4);
      bf16x8 ob;
      #pragma unroll
      for (int j = 0; j < 4; ++j) { ob[j] = f2bf(a0[j]); ob[4 + j] = f2bf(a1[j]); }
      *(bf16x8*)(efb + (size_t)pos * ED + part * 8) = ob;
      if (part == 0) ccol[pos] = (unsigned short)c;
    }
  } else {
    // ---- chunk bounds: cb[k] = {first n with row_ptr>=k*CH, first n with row_ptr>=(k+1)*CH}
    int k = (b - SGB - SCB) * 256 + threadIdx.x;
    if (k < nchunks) {
      int t0 = k * CH, t1 = t0 + CH;
      int lo = 0, hi = N;
      while (lo < hi) { int mid = (lo + hi) >> 1; if (row_ptr[mid] < t0) lo = mid + 1; else hi = mid; }
      int na = lo;
      hi = N;
      while (lo < hi) { int mid = (lo + hi) >> 1; if (row_ptr[mid] < t1) lo = mid + 1; else hi = mid; }
      cb[k] = make_int2(na, lo);
    }
  }
}

// --- layer 1 + segment reduce: chunk-balanced, 2 waves/block (col halves),
//     efb/ccol streamed coalesced, g gathered from L2 ---
__global__ __launch_bounds__(128, 4) void layer1_kernel(
    const float* __restrict__ s2, const short* __restrict__ g2,
    const short* __restrict__ efb, const unsigned short* __restrict__ ccol,
    const short* __restrict__ w1eA, const int* __restrict__ row_ptr,
    const int2* __restrict__ cb, float* __restrict__ hsum) {
  int2 bounds = cb[blockIdx.x];
  int na = bounds.x, nb = bounds.y;
  if (na >= nb) return;
  int lane = threadIdx.x & 63;
  int w = threadIdx.x >> 6;  // col half 0/1
  int li = lane & 15, lg = lane >> 4;

  bf16x8 wa[4];
  #pragma unroll
  for (int nt = 0; nt < 4; ++nt)
    wa[nt] = *(const bf16x8*)(w1eA + ((w * 4 + nt) * 64 + lane) * 8);

  for (int n = na; n < nb; ++n) {
    int rp = row_ptr[n], rpe = row_ptr[n + 1];
    int deg = rpe - rp;
    f32x4 sreg[4];
    #pragma unroll
    for (int nt = 0; nt < 4; ++nt)
      sreg[nt] = *(const f32x4*)(s2 + (size_t)n * 128 + w * 64 + lg * 16 + nt * 4);
    f32x4 psum[4];
    #pragma unroll
    for (int nt = 0; nt < 4; ++nt) psum[nt] = (f32x4){0.f, 0.f, 0.f, 0.f};

    int ntiles = (deg + 15) >> 4;
    int last = rpe - 1;
    auto ldpos = [&](int t) {
      int p = rp + t * 16 + li;
      return p > last ? last : p;
    };

    // pipeline prologue: tiles 0 and 1 staged; g for tile 0 in flight
    int pA = ldpos(0), pB = ldpos(1);
    int cA = ccol[pA], cB = ccol[pB];
    bf16x8 eA = *(const bf16x8*)(efb + (size_t)pA * ED + lg * 8);
    bf16x8 eB = *(const bf16x8*)(efb + (size_t)pB * ED + lg * 8);
    const short* gpA = g2 + (size_t)cA * 128 + w * 64 + lg * 16;
    bf16x8 gA0 = *(const bf16x8*)gpA;
    bf16x8 gA1 = *(const bf16x8*)(gpA + 8);

    for (int t = 0; t < ntiles; ++t) {
      // prefetch tile t+1's g (col already resident) and tile t+2's pos/col/efb
      const short* gpB = g2 + (size_t)cB * 128 + w * 64 + lg * 16;
      bf16x8 gB0 = *(const bf16x8*)gpB;
      bf16x8 gB1 = *(const bf16x8*)(gpB + 8);
      int pC = ldpos(t + 2);
      int cC = ccol[pC];
      bf16x8 eC = *(const bf16x8*)(efb + (size_t)pC * ED + lg * 8);
      // compute tile t
      f32x4 a0 = __builtin_amdgcn_mfma_f32_16x16x32_bf16(wa[0], eA, (f32x4){0.f,0.f,0.f,0.f}, 0, 0, 0);
      f32x4 a1 = __builtin_amdgcn_mfma_f32_16x16x32_bf16(wa[1], eA, (f32x4){0.f,0.f,0.f,0.f}, 0, 0, 0);
      f32x4 a2 = __builtin_amdgcn_mfma_f32_16x16x32_bf16(wa[2], eA, (f32x4){0.f,0.f,0.f,0.f}, 0, 0, 0);
      f32x4 a3 = __builtin_amdgcn_mfma_f32_16x16x32_bf16(wa[3], eA, (f32x4){0.f,0.f,0.f,0.f}, 0, 0, 0);
      if ((t * 16 + li) < deg) {
        f32x4 v0 = a0 + sreg[0] + bf8lo(gA0);
        f32x4 v1 = a1 + sreg[1] + bf8hi(gA0);
        f32x4 v2 = a2 + sreg[2] + bf8lo(gA1);
        f32x4 v3 = a3 + sreg[3] + bf8hi(gA1);
        #pragma unroll
        for (int r = 0; r < 4; ++r) {
          psum[0][r] += (v0[r] > 0.f ? v0[r] : 0.f);
          psum[1][r] += (v1[r] > 0.f ? v1[r] : 0.f);
          psum[2][r] += (v2[r] > 0.f ? v2[r] : 0.f);
          psum[3][r] += (v3[r] > 0.f ? v3[r] : 0.f);
        }
      }
      // rotate
      cB = cC; eA = eB; eB = eC;
      gA0 = gB0; gA1 = gB1;
    }

    // reduce over the 16 li-lanes (edges), store this wave's col-half
    #pragma unroll
    for (int nt = 0; nt < 4; ++nt)
      #pragma unroll
      for (int r = 0; r < 4; ++r) {
        float v = psum[nt][r];
        v += __shfl_xor(v, 1);
        v += __shfl_xor(v, 2);
        v += __shfl_xor(v, 4);
        v += __shfl_xor(v, 8);
        psum[nt][r] = v;
      }
    if (li == 0) {
      #pragma unroll
      for (int nt = 0; nt < 4; ++nt)
        *(f32x4*)(hsum + (size_t)n * 128 + w * 64 + nt * 16 + lg * 4) = psum[nt];
    }
  }
}

// --- out = Hsum @ W2 + deg*b2 ; 4 waves x 16 rows per block ---
__global__ __launch_bounds__(256) void out_kernel(const float* __restrict__ hsum,
                                                  const short* __restrict__ w2t,
                                                  const float* __restrict__ b2,
                                                  const int* __restrict__ row_ptr,
                                                  float* __restrict__ out, int N) {
  int lane = threadIdx.x & 63, w = threadIdx.x >> 6;
  int li = lane & 15, lg = lane >> 4;
  int base = blockIdx.x * 64 + w * 16;
  int rowm = base + li;
  if (rowm >= N) rowm = N - 1;
  float breg[8];
  #pragma unroll
  for (int nt = 0; nt < 8; ++nt) breg[nt] = b2[nt * 16 + li];
  f32x4 acc[8];
  #pragma unroll
  for (int nt = 0; nt < 8; ++nt) acc[nt] = (f32x4){0.f, 0.f, 0.f, 0.f};
  #pragma unroll
  for (int kc = 0; kc < 4; ++kc) {
    f32x4 f0 = *(const f32x4*)(hsum + (size_t)rowm * 128 + kc * 32 + lg * 8);
    f32x4 f1 = *(const f32x4*)(hsum + (size_t)rowm * 128 + kc * 32 + lg * 8 + 4);
    bf16x8 a;
    #pragma unroll
    for (int j = 0; j < 4; ++j) { a[j] = f2bf(f0[j]); a[4 + j] = f2bf(f1[j]); }
    #pragma unroll
    for (int nt = 0; nt < 8; ++nt) {
      bf16x8 bb = *(const bf16x8*)(w2t + (nt * 16 + li) * 128 + kc * 32 + lg * 8);
      acc[nt] = __builtin_amdgcn_mfma_f32_16x16x32_bf16(a, bb, acc[nt], 0, 0, 0);
    }
  }
  #pragma unroll
  for (int r = 0; r < 4; ++r) {
    int row = base + lg * 4 + r;
    if (row < N) {
      float dg = (float)(row_ptr[row + 1] - row_ptr[row]);
      #pragma unroll
      for (int nt = 0; nt < 8; ++nt)
        out[(size_t)row * 128 + nt * 16 + li] = acc[nt][r] + dg * breg[nt];
    }
  }
}

extern "C" void kernel_launch(void* const* d_in, const int* in_sizes, int n_in,
                              void* d_out, int out_size, void* d_ws, size_t ws_size,
                              hipStream_t stream) {
  const float* h  = (const float*)d_in[0];
  const void*  ei = d_in[1];
  const float* ef = (const float*)d_in[2];
  const float* W1 = (const float*)d_in[4];
  const float* b1 = (const float*)d_in[5];
  const float* W2 = (const float*)d_in[6];
  const float* b2 = (const float*)d_in[7];
  float* out = (float*)d_out;
  int N = in_sizes[0] / ND;
  int E = in_sizes[2] / ED;
  int nchunks = (E + CH - 1) / CH;

  char* ws = (char*)d_ws;
  size_t off = 0;
  auto alloc = [&](size_t bytes) {
    size_t o = off;
    off = (off + bytes + 255) & ~(size_t)255;
    return o;
  };
  int*            flag    = (int*)(ws + alloc(4));
  int*            counts  = (int*)(ws + alloc((size_t)N * 4));
  int*            row_ptr = (int*)(ws + alloc((size_t)(N + 1) * 4));
  int*            rank    = (int*)(ws + alloc((size_t)E * 4));
  unsigned int*   rc      = (unsigned int*)(ws + alloc((size_t)E * 4));
  short*          w12t    = (short*)(ws + alloc(256 * 128 * 2));
  short*          w1eA    = (short*)(ws + alloc(8 * 64 * 8 * 2));
  short*          w2t     = (short*)(ws + alloc(128 * 128 * 2));
  float*          s2      = (float*)(ws + alloc((size_t)N * 128 * 4));
  short*          g2      = (short*)(ws + alloc((size_t)N * 128 * 2));
  float*          hsumb   = (float*)(ws + alloc((size_t)N * 128 * 4));
  short*          efb     = (short*)(ws + alloc((size_t)E * ED * 2));
  unsigned short* ccol    = (unsigned short*)(ws + alloc((size_t)E * 2));
  int2*           cbb     = (int2*)(ws + alloc((size_t)nchunks * 8));

  int SGB = (N + 63) >> 6;
  int SCB = (4 * E + 255) >> 8;
  int CBB = (nchunks + 255) >> 8;

  prep_kernel<<<128, 256, 0, stream>>>(W1, W2, (const unsigned int*)ei, w12t, w1eA, w2t,
                                       flag, counts, N);
  hist_kernel<<<(E + 255) / 256, 256, 0, stream>>>(ei, flag, counts, rank, rc, E);
  scan_kernel<<<1, 1024, 0, stream>>>(counts, row_ptr, N);
  scatter_sg_kernel<<<SGB + SCB + CBB, 256, 0, stream>>>(
      ef, row_ptr, rank, rc, h, w12t, b1, efb, ccol, cbb, s2, g2, N, E, nchunks);
  layer1_kernel<<<nchunks, 128, 0, stream>>>(s2, g2, efb, ccol, w1eA, row_ptr, cbb, hsumb);
  out_kernel<<<(N + 63) / 64, 256, 0, stream>>>(hsumb, w2t, b2, row_ptr, out, N);
}